// Round 1
// baseline (12793.589 us; speedup 1.0000x reference)
//
#include <hip/hip_runtime.h>
#include <hip/hip_bf16.h>

// ---------------------------------------------------------------------------
// Problem constants
//   B=256 batch, F=512, H=1024, N=128 (n SPD mats), L=3, M=16 (SPD side)
// Barycenter reformulated via OT transport maps:
//   R_i = A_i^{1/2} (precomputed, Newton-Schulz)
//   per iter: P_i = R_i (R_i S R_i)^{-1/2} R_i ; W = sum_i w_i P_i ; S' = W S W
// Equivalent to the reference fixed point (unique SPD T with T S T = A).
// ---------------------------------------------------------------------------

#define NS_R    14   // NS iters for A_i^{1/2}
#define NS_SAND 18   // NS iters for sandwich inverse-sqrt

// --- 16x16 matmul, column-distributed across a 16-lane group --------------
// Lane c (threadIdx&15) holds X[:,c] of every matrix. C = A*B.
__device__ __forceinline__ void mm16(const float* A, const float* B, float* C) {
#pragma unroll
  for (int r = 0; r < 16; ++r) C[r] = 0.f;
#pragma unroll
  for (int k = 0; k < 16; ++k) {
    float bk = B[k];
#pragma unroll
    for (int r = 0; r < 16; ++r) {
      C[r] = fmaf(__shfl(A[r], k, 16), bk, C[r]);
    }
  }
}

// Coupled Newton-Schulz: on entry Y = M (SPD, cols). On exit:
// Y ~= (M/cn)^{1/2}, Z ~= (M/cn)^{-1/2}, returns cn = ||M||_F (>= lam_max).
__device__ __forceinline__ float ns_pair(float* Y, float* Z, int c, int iters) {
  float s = 0.f;
#pragma unroll
  for (int r = 0; r < 16; ++r) s += Y[r] * Y[r];
#pragma unroll
  for (int off = 1; off < 16; off <<= 1) s += __shfl_xor(s, off, 16);
  float cn = sqrtf(s);
  float inv = 1.f / cn;
#pragma unroll
  for (int r = 0; r < 16; ++r) Y[r] *= inv;
#pragma unroll
  for (int r = 0; r < 16; ++r) Z[r] = (r == c) ? 1.f : 0.f;
  float T[16], U[16];
#pragma unroll 1
  for (int it = 0; it < iters; ++it) {
    mm16(Z, Y, U);                       // U = Z*Y
#pragma unroll
    for (int r = 0; r < 16; ++r) T[r] = ((r == c) ? 1.5f : 0.f) - 0.5f * U[r];
    mm16(Y, T, U);                       // Y' = Y*T
#pragma unroll
    for (int r = 0; r < 16; ++r) Y[r] = U[r];
    mm16(T, Z, U);                       // Z' = T*Z
#pragma unroll
    for (int r = 0; r < 16; ++r) Z[r] = U[r];
  }
  return cn;
}

// --- GEMM + bias: C[M,N] = A[M,K]*B[K,N] + bias[N] -------------------------
__global__ __launch_bounds__(256) void gemm_bias_kernel(
    const float* __restrict__ A, const float* __restrict__ B,
    const float* __restrict__ bias, float* __restrict__ C,
    int Md, int Nd, int Kd) {
  __shared__ float As[16][65];
  __shared__ float Bs[16][68];
  int tx = threadIdx.x & 15, ty = threadIdx.x >> 4;
  float acc[4][4] = {};
  for (int k0 = 0; k0 < Kd; k0 += 16) {
#pragma unroll
    for (int i = 0; i < 4; ++i) {
      int idx = i * 256 + threadIdx.x;
      int am = idx >> 4, ak = idx & 15;
      As[ak][am] = A[(blockIdx.y * 64 + am) * Kd + k0 + ak];
      int bn = idx & 63, bk = idx >> 6;
      Bs[bk][bn] = B[(k0 + bk) * Nd + blockIdx.x * 64 + bn];
    }
    __syncthreads();
#pragma unroll
    for (int kk = 0; kk < 16; ++kk) {
      float av[4], bv[4];
#pragma unroll
      for (int i = 0; i < 4; ++i) av[i] = As[kk][ty * 4 + i];
#pragma unroll
      for (int j = 0; j < 4; ++j) bv[j] = Bs[kk][tx * 4 + j];
#pragma unroll
      for (int i = 0; i < 4; ++i)
#pragma unroll
        for (int j = 0; j < 4; ++j) acc[i][j] = fmaf(av[i], bv[j], acc[i][j]);
    }
    __syncthreads();
  }
#pragma unroll
  for (int i = 0; i < 4; ++i)
#pragma unroll
    for (int j = 0; j < 4; ++j) {
      int m = blockIdx.y * 64 + ty * 4 + i;
      int n = blockIdx.x * 64 + tx * 4 + j;
      C[m * Nd + n] = acc[i][j] + bias[n];
    }
}

// --- column-wise Norm_E2M (over 256 rows) + optional relu/residual ---------
__global__ __launch_bounds__(256) void colnorm_kernel(
    const float* __restrict__ z, const float* __restrict__ alpha,
    const float* __restrict__ bias, const float* __restrict__ resid,
    float* __restrict__ out, int N, int do_relu) {
  int c = threadIdx.x & 63;
  int g = threadIdx.x >> 6;  // 0..3
  int col = blockIdx.x * 64 + c;
  float s1 = 0.f, s2 = 0.f;
  for (int r = g * 64; r < g * 64 + 64; ++r) {
    float v = z[r * N + col];
    s1 += v; s2 += v * v;
  }
  __shared__ float sm1[4][64], sm2[4][64], smu[64], srs[64];
  sm1[g][c] = s1; sm2[g][c] = s2;
  __syncthreads();
  if (g == 0) {
    float a = sm1[0][c] + sm1[1][c] + sm1[2][c] + sm1[3][c];
    float b = sm2[0][c] + sm2[1][c] + sm2[2][c] + sm2[3][c];
    float mu = a * (1.f / 256.f);
    float var = fmaxf(b * (1.f / 256.f) - mu * mu, 0.f);
    smu[c] = mu;
    srs[c] = 1.f / (sqrtf(var) + 1e-6f);
  }
  __syncthreads();
  float mu = smu[c], rs = srs[c];
  float al = alpha[col], bi = bias[col];
  for (int r = g * 64; r < g * 64 + 64; ++r) {
    float v = (z[r * N + col] - mu) * rs * al + bi;
    if (do_relu) v = fmaxf(v, 0.f);
    float o = resid ? (resid[r * N + col] + v) : v;
    out[r * N + col] = o;
  }
}

// --- row softmax over 128 cols; one wave per row ---------------------------
__global__ __launch_bounds__(256) void softmax_kernel(
    const float* __restrict__ lg, float* __restrict__ w) {
  int wv = threadIdx.x >> 6;
  int lane = threadIdx.x & 63;
  int row = blockIdx.x * 4 + wv;
  float a = lg[row * 128 + lane];
  float b = lg[row * 128 + 64 + lane];
  float m = fmaxf(a, b);
#pragma unroll
  for (int off = 32; off; off >>= 1) m = fmaxf(m, __shfl_xor(m, off, 64));
  float ea = expf(a - m), eb = expf(b - m);
  float s = ea + eb;
#pragma unroll
  for (int off = 32; off; off >>= 1) s += __shfl_xor(s, off, 64);
  float inv = 1.f / s;
  w[row * 128 + lane] = ea * inv;
  w[row * 128 + 64 + lane] = eb * inv;
}

// --- R_i = A_i^{1/2}; grid 8 x 256 (16 groups each, 1 matrix per group) ----
__global__ __launch_bounds__(256) void sqrtA_kernel(
    const float* __restrict__ A, float* __restrict__ R) {
  int c = threadIdx.x & 15;
  int g = threadIdx.x >> 4;
  int i = blockIdx.x * 16 + g;
  float Y[16], Z[16];
#pragma unroll
  for (int r = 0; r < 16; ++r) Y[r] = A[i * 256 + c * 16 + r];  // symmetric
  float cn = ns_pair(Y, Z, c, NS_R);
  float sc = sqrtf(cn);
#pragma unroll
  for (int r = 0; r < 16; ++r) R[i * 256 + c * 16 + r] = Y[r] * sc;
}

// --- init: S = I per batch, wsacc = 0 --------------------------------------
__global__ __launch_bounds__(256) void bary_init(float* __restrict__ S,
                                                 float* __restrict__ wac) {
  int t = blockIdx.x * 256 + threadIdx.x;
  int e = t & 255;
  S[t] = ((e >> 4) == (e & 15)) ? 1.f : 0.f;
  wac[t] = 0.f;
}

// --- main per-iteration kernel: one sandwich per 16-lane group -------------
__global__ __launch_bounds__(256) void bary_sand(
    const float* __restrict__ R, const float* __restrict__ S,
    const float* __restrict__ wts, float* __restrict__ wac) {
  int c = threadIdx.x & 15;
  int g = threadIdx.x >> 4;            // 0..15
  int b = blockIdx.x >> 3;             // batch
  int i = ((blockIdx.x & 7) << 4) | g; // sandwich index 0..127
  float Rr[16], Sc[16], T0[16], M[16], Z[16];
#pragma unroll
  for (int r = 0; r < 16; ++r) Rr[r] = R[i * 256 + c * 16 + r];
#pragma unroll
  for (int r = 0; r < 16; ++r) Sc[r] = S[b * 256 + c * 16 + r];
  mm16(Rr, Sc, T0);   // T0 = R*S
  mm16(T0, Rr, M);    // M  = R*S*R
  float cn = ns_pair(M, Z, c, NS_SAND);  // Z ~= (M/cn)^{-1/2}
  mm16(Rr, Z, T0);    // T0 = R*Z
  mm16(T0, Rr, M);    // M  = R*Z*R  (P_i up to scale)
  float wgt = wts[b * 128 + i] * (1.f / sqrtf(cn));
  __shared__ float red[16 * 257];
#pragma unroll
  for (int r = 0; r < 16; ++r) red[g * 257 + r * 16 + c] = M[r] * wgt;
  __syncthreads();
  int t = threadIdx.x;
  float acc = 0.f;
#pragma unroll
  for (int gg = 0; gg < 16; ++gg) acc += red[gg * 257 + t];
  atomicAdd(&wac[b * 256 + t], acc);
}

// --- S' = W S W ; zero accumulator; 16 groups = 16 batches per block -------
__global__ __launch_bounds__(256) void bary_update(float* __restrict__ wac,
                                                   float* __restrict__ S) {
  int c = threadIdx.x & 15;
  int g = threadIdx.x >> 4;
  int b = blockIdx.x * 16 + g;
  float W[16], Sc[16], T0[16], T1[16];
#pragma unroll
  for (int r = 0; r < 16; ++r) W[r] = wac[b * 256 + c * 16 + r];  // ~symmetric
#pragma unroll
  for (int r = 0; r < 16; ++r) Sc[r] = S[b * 256 + c * 16 + r];
  mm16(W, Sc, T0);
  mm16(T0, W, T1);
#pragma unroll
  for (int r = 0; r < 16; ++r) S[b * 256 + c * 16 + r] = T1[r];
#pragma unroll
  for (int r = 0; r < 16; ++r) wac[b * 256 + c * 16 + r] = 0.f;
}

__global__ __launch_bounds__(256) void copy_out_kernel(
    const float* __restrict__ S, float* __restrict__ out) {
  int t = blockIdx.x * 256 + threadIdx.x;
  out[t] = S[t];
}

extern "C" void kernel_launch(void* const* d_in, const int* in_sizes, int n_in,
                              void* d_out, int out_size, void* d_ws, size_t ws_size,
                              hipStream_t stream) {
  const float* x        = (const float*)d_in[0];
  const float* y_train  = (const float*)d_in[1];
  const float* W1       = (const float*)d_in[2];
  const float* b1       = (const float*)d_in[3];
  const float* alpha1   = (const float*)d_in[4];
  const float* bias1    = (const float*)d_in[5];
  const float* Wh       = (const float*)d_in[6];
  const float* bh       = (const float*)d_in[7];
  const float* alpha_h  = (const float*)d_in[8];
  const float* bias_h   = (const float*)d_in[9];
  const float* Wout     = (const float*)d_in[10];
  const float* bout     = (const float*)d_in[11];
  const float* alpha_o  = (const float*)d_in[12];
  const float* bias_o   = (const float*)d_in[13];
  float* out = (float*)d_out;
  float* ws  = (float*)d_ws;

  float* h   = ws;             // 256*1024
  float* z   = ws + 262144;    // 256*1024
  float* lg  = ws + 524288;    // 256*128
  float* wts = ws + 557056;    // 256*128
  float* Rm  = ws + 589824;    // 128*256
  float* Sb  = ws + 622592;    // 256*256
  float* wac = ws + 688128;    // 256*256

  // ---- MLP ----
  gemm_bias_kernel<<<dim3(16, 4), 256, 0, stream>>>(x, W1, b1, z, 256, 1024, 512);
  colnorm_kernel<<<16, 256, 0, stream>>>(z, alpha1, bias1, nullptr, h, 1024, 1);
  for (int l = 0; l < 3; ++l) {
    gemm_bias_kernel<<<dim3(16, 4), 256, 0, stream>>>(
        h, Wh + (size_t)l * 1048576, bh + l * 1024, z, 256, 1024, 1024);
    colnorm_kernel<<<16, 256, 0, stream>>>(
        z, alpha_h + l * 1024, bias_h + l * 1024, h, h, 1024, 1);
  }
  gemm_bias_kernel<<<dim3(2, 4), 256, 0, stream>>>(h, Wout, bout, z, 256, 128, 1024);
  colnorm_kernel<<<2, 256, 0, stream>>>(z, alpha_o, bias_o, nullptr, lg, 128, 0);
  softmax_kernel<<<64, 256, 0, stream>>>(lg, wts);

  // ---- barycenter ----
  sqrtA_kernel<<<8, 256, 0, stream>>>(y_train, Rm);
  bary_init<<<256, 256, 0, stream>>>(Sb, wac);
  for (int it = 0; it < 10; ++it) {
    bary_sand<<<2048, 256, 0, stream>>>(Rm, Sb, wts, wac);
    bary_update<<<16, 256, 0, stream>>>(wac, Sb);
  }
  copy_out_kernel<<<256, 256, 0, stream>>>(Sb, out);
}